// Round 1
// baseline (381.410 us; speedup 1.0000x reference)
//
#include <hip/hip_runtime.h>

// Causal MHA forward, B=4 S=2048 H=16 D=128, fp32 BSHD in/out.
// Flash-attention: block = 128 q-rows x (b,h); 8 waves x 16 rows; BK=32 key tiles.
// bf16 MFMA 16x16x32 (tolerance 8.1e-2 permits bf16 compute).

typedef short bf16x8 __attribute__((ext_vector_type(8)));
typedef short bf16x4 __attribute__((ext_vector_type(4)));
typedef short bf16x2 __attribute__((ext_vector_type(2)));
typedef float f32x4  __attribute__((ext_vector_type(4)));

#define SEQ 2048
#define NH  16
#define HD  128
#define BQ  128
#define BK  32
#define KSTR 136   // K tile row stride (bf16 elems): 272B, 16B-aligned, breaks bank pow2
#define VSTR 44    // V^T row stride: 88B, 8B-aligned (b64-pair reads), conflict-light
#define PSTR 40    // P row stride: 80B, 16B-aligned

__device__ __forceinline__ short f2bf(float f) {  // RNE fp32 -> bf16 bits
  unsigned u = __builtin_bit_cast(unsigned, f);
  u = (u + 0x7FFFu + ((u >> 16) & 1u)) >> 16;
  return (short)u;
}

__global__ __launch_bounds__(512, 4) void fa_fwd(
    const float* __restrict__ Qg, const float* __restrict__ Kg,
    const float* __restrict__ Vg, float* __restrict__ Og)
{
  __shared__ __align__(16) short Klds[BK * KSTR];    //  8704 B
  __shared__ __align__(16) short Vtlds[HD * VSTR];   // 11264 B
  __shared__ __align__(16) short Plds[8 * 16 * PSTR];// 10240 B

  const float qscale = 0.08838834764831845f * 1.4426950408889634f; // 1/sqrt(D)*log2(e)
  const int tid  = threadIdx.x;
  const int w    = tid >> 6;        // wave 0..7
  const int lane = tid & 63;
  const int L    = lane & 15;
  const int quad = lane >> 4;

  // bh = bid%64: same-(b,h) q-tiles land on the same XCD (bid%8) for K/V L2 reuse.
  // qi reversed: longest causal blocks dispatch first.
  const int bh = (int)blockIdx.x & 63;
  const int qi = 15 - ((int)blockIdx.x >> 6);
  const int bb = bh >> 4;
  const int hh = bh & 15;
  const int q0 = qi << 7;
  const int wrow0 = q0 + w * 16;

  // ---- Q fragments: A-layout [m=lane&15][k=quad*8+j], pre-scaled ----
  const float* qp = Qg + ((bb * SEQ + (wrow0 + L)) * NH + hh) * HD;
  bf16x8 aq[4];
#pragma unroll
  for (int dk = 0; dk < 4; ++dk) {
    const float4 a = *(const float4*)(qp + dk * 32 + quad * 8);
    const float4 b = *(const float4*)(qp + dk * 32 + quad * 8 + 4);
    aq[dk][0] = f2bf(a.x * qscale); aq[dk][1] = f2bf(a.y * qscale);
    aq[dk][2] = f2bf(a.z * qscale); aq[dk][3] = f2bf(a.w * qscale);
    aq[dk][4] = f2bf(b.x * qscale); aq[dk][5] = f2bf(b.y * qscale);
    aq[dk][6] = f2bf(b.z * qscale); aq[dk][7] = f2bf(b.w * qscale);
  }

  f32x4 O[8];
#pragma unroll
  for (int dn = 0; dn < 8; ++dn) O[dn] = (f32x4){0.f, 0.f, 0.f, 0.f};
  float m_r[4] = {-1e30f, -1e30f, -1e30f, -1e30f};
  float l_r[4] = {0.f, 0.f, 0.f, 0.f};

  const int kkey = tid >> 4;          // 0..31
  const int kdp  = (tid & 15) << 3;   // 0..120
  const int vdc  = tid >> 4;          // 0..31
  const int vkp  = tid & 15;          // 0..15

  for (int kv0 = 0; kv0 < q0 + BQ; kv0 += BK) {
    // ---- stage K tile (row-major bf16) ----
    {
      const float* kr = Kg + ((bb * SEQ + kv0 + kkey) * NH + hh) * HD + kdp;
      float4 k0 = *(const float4*)kr;
      float4 k1 = *(const float4*)(kr + 4);
      bf16x8 kb;
      kb[0] = f2bf(k0.x); kb[1] = f2bf(k0.y); kb[2] = f2bf(k0.z); kb[3] = f2bf(k0.w);
      kb[4] = f2bf(k1.x); kb[5] = f2bf(k1.y); kb[6] = f2bf(k1.z); kb[7] = f2bf(k1.w);
      *(bf16x8*)&Klds[kkey * KSTR + kdp] = kb;
    }
    // ---- stage V tile transposed: Vt[d][key], paired-key b32 writes ----
    {
      const float* vr = Vg + ((bb * SEQ + kv0 + 2 * vkp) * NH + hh) * HD + vdc * 4;
      float4 v0 = *(const float4*)vr;
      float4 v1 = *(const float4*)(vr + NH * HD);
      float f0[4] = {v0.x, v0.y, v0.z, v0.w};
      float f1[4] = {v1.x, v1.y, v1.z, v1.w};
#pragma unroll
      for (int i = 0; i < 4; ++i) {
        bf16x2 pr; pr[0] = f2bf(f0[i]); pr[1] = f2bf(f1[i]);
        *(bf16x2*)&Vtlds[(vdc * 4 + i) * VSTR + 2 * vkp] = pr;
      }
    }
    __syncthreads();

    if (kv0 <= wrow0 + 15) {   // wave has at least one unmasked row in this tile
      // ---- S = Q K^T (two 16-col chunks) ----
      f32x4 s0 = {0.f, 0.f, 0.f, 0.f}, s1 = {0.f, 0.f, 0.f, 0.f};
#pragma unroll
      for (int dk = 0; dk < 4; ++dk) {
        bf16x8 b0 = *(const bf16x8*)&Klds[L * KSTR + dk * 32 + quad * 8];
        bf16x8 b1 = *(const bf16x8*)&Klds[(L + 16) * KSTR + dk * 32 + quad * 8];
        s0 = __builtin_amdgcn_mfma_f32_16x16x32_bf16(aq[dk], b0, s0, 0, 0, 0);
        s1 = __builtin_amdgcn_mfma_f32_16x16x32_bf16(aq[dk], b1, s1, 0, 0, 0);
      }
      // ---- causal mask (only tiles overlapping the diagonal) ----
      if (kv0 + BK - 1 > wrow0) {
#pragma unroll
        for (int r = 0; r < 4; ++r) {
          const int row = wrow0 + quad * 4 + r;
          if (kv0 + L > row)      s0[r] = -1e30f;
          if (kv0 + 16 + L > row) s1[r] = -1e30f;
        }
      }
      // ---- online softmax (rows live in C-layout: row = quad*4+r) ----
      float al[4];
#pragma unroll
      for (int r = 0; r < 4; ++r) {
        float v = fmaxf(s0[r], s1[r]);
        v = fmaxf(v, __shfl_xor(v, 1));
        v = fmaxf(v, __shfl_xor(v, 2));
        v = fmaxf(v, __shfl_xor(v, 4));
        v = fmaxf(v, __shfl_xor(v, 8));
        const float mnew = fmaxf(m_r[r], v);
        al[r] = __builtin_amdgcn_exp2f(m_r[r] - mnew);
        const float p0 = __builtin_amdgcn_exp2f(s0[r] - mnew);
        const float p1 = __builtin_amdgcn_exp2f(s1[r] - mnew);
        float rs = p0 + p1;
        rs += __shfl_xor(rs, 1);
        rs += __shfl_xor(rs, 2);
        rs += __shfl_xor(rs, 4);
        rs += __shfl_xor(rs, 8);
        l_r[r] = l_r[r] * al[r] + rs;
        m_r[r] = mnew;
        short* pp = &Plds[(w * 16 + quad * 4 + r) * PSTR];
        pp[L]      = f2bf(p0);
        pp[16 + L] = f2bf(p1);
      }
      // ---- rescale O ----
#pragma unroll
      for (int dn = 0; dn < 8; ++dn) {
#pragma unroll
        for (int r = 0; r < 4; ++r) O[dn][r] *= al[r];
      }
      // ---- O += P V : P re-read in A-layout, Vt rows give B-layout ----
      bf16x8 pa = *(const bf16x8*)&Plds[(w * 16 + L) * PSTR + quad * 8];
#pragma unroll
      for (int dn = 0; dn < 8; ++dn) {
        const int off = (dn * 16 + L) * VSTR + quad * 8;
        bf16x4 vlo = *(const bf16x4*)&Vtlds[off];
        bf16x4 vhi = *(const bf16x4*)&Vtlds[off + 4];
        bf16x8 vb = __builtin_shufflevector(vlo, vhi, 0, 1, 2, 3, 4, 5, 6, 7);
        O[dn] = __builtin_amdgcn_mfma_f32_16x16x32_bf16(pa, vb, O[dn], 0, 0, 0);
      }
    }
    __syncthreads();
  }

  // ---- epilogue: divide by row sum, store fp32 ----
#pragma unroll
  for (int r = 0; r < 4; ++r) {
    const float inv = 1.0f / l_r[r];
    const int row = wrow0 + quad * 4 + r;
    float* op = Og + ((bb * SEQ + row) * NH + hh) * HD;
#pragma unroll
    for (int dn = 0; dn < 8; ++dn) op[dn * 16 + L] = O[dn][r] * inv;
  }
}

extern "C" void kernel_launch(void* const* d_in, const int* in_sizes, int n_in,
                              void* d_out, int out_size, void* d_ws, size_t ws_size,
                              hipStream_t stream) {
  const float* q = (const float*)d_in[0];
  const float* k = (const float*)d_in[1];
  const float* v = (const float*)d_in[2];
  float* o = (float*)d_out;
  dim3 grid(64 * (SEQ / BQ));   // 64 (b,h) x 16 q-tiles = 1024 blocks
  dim3 block(512);
  fa_fwd<<<grid, block, 0, stream>>>(q, k, v, o);
}